// Round 7
// baseline (674.366 us; speedup 1.0000x reference)
//
#include <hip/hip_runtime.h>
#include <hip/hip_fp16.h>

// DiffusionConv: out = x@Tf0 + Px@(Tb0+Tb1) + P2x@(Tf1+Tb2) + P3x@Tf2
// R21: prop floor identified (R20 counters): per-XCD compulsory L2 misses --
// each of 8 non-coherent XCD L2s re-fetches the whole 6.4MB gather table
// (FETCH 42MB, served ~1.4TB/s at the per-CU miss-queue limit) => 30us/prop
// regardless of inner-loop structure. Fix:
//  - tables stored SLICE-MAJOR [8][NPADL][8ch]; slice pinned to XCD via
//    blockIdx&7 => per-XCD slice footprint 0.8MB, L2-resident.
//  - decode kernel folds w*dinv[col] into bkt2 once.
//  - ONE persistent kernel runs all 3 props; meta (20 slots/node) cached in
//    LDS across props; 2 global sense-reversing barriers (agent-scope
//    atomics + threadfence => correct even if XCD mapping differs; mapping
//    is perf-only). LDS 45KB/block => exactly 3 blocks/CU => 768 blocks all
//    co-resident (no deadlock).
//  - gemm separate dispatch, slice-major A-loads (R19-verified otherwise).
// scatter2 edge phase + build verbatim R18.

#define N_NODES 50000
#define N_EDGES 800000
#define C 64
#define CAP 64          // bucket capacity; rows ~ Poisson(16), P(>64) ~ 2e-18
#define NPART 196       // partitions of 256 rows: p = r >> 8
#define CAPP 4608       // edges per partition region; mean 4096, +8 sigma
#define EPB 8192        // edges per block in scatter2
#define NEB 98          // ceil(800000/8192)
#define XH_BLOCKS 782   // ceil(800000 float4 chunks / 1024)
#define CW_BLOCKS 16    // 16384 weight elems / 1024
#define NPADL 50176
#define NSLICE 8
#define NGRP 96         // node groups; grid = NGRP*NSLICE = 768 = 3 blocks/CU
#define FBLK 768
#define NPBK 521        // nodes per group: 96*521 = 50016 >= 50000
#define MSLOT 20        // LDS-cached meta slots/node; tail via global bkt2
#define GB 782          // ceil(50000/64) gemm row-tiles

typedef _Float16 half8 __attribute__((ext_vector_type(8)));
typedef float f32x4 __attribute__((ext_vector_type(4)));

// Fused: blocks [0,NEB): hist+reserve+scatter; [NEB,NEB+XH): x fp32->fp16
// into SLICE-MAJOR xh[8][NPADL][8]; [NEB+XH,..): weights -> whc[j][co][ci]
__global__ __launch_bounds__(1024) void scatter2_kernel(
        const int* __restrict__ row, const int* __restrict__ col,
        const float* __restrict__ w, int* __restrict__ percur,
        uint2* __restrict__ pedges,
        const float* __restrict__ x, __half* __restrict__ xh,
        const float* __restrict__ tf, const float* __restrict__ tb,
        _Float16* __restrict__ whc) {
    const int tid = threadIdx.x;
    if (blockIdx.x >= NEB + XH_BLOCKS) {
        int idx = (blockIdx.x - NEB - XH_BLOCKS) * 1024 + tid;  // < 16384
        int j = idx >> 12;
        int rem = idx & 4095;   // ci*64 + co
        int ci = rem >> 6;
        int co = rem & 63;
        float v;
        if (j == 0)      v = tf[rem];                         // Tf0
        else if (j == 1) v = tb[rem] + tb[4096 + rem];        // Tb0 + Tb1
        else if (j == 2) v = tf[4096 + rem] + tb[8192 + rem]; // Tf1 + Tb2
        else             v = tf[8192 + rem];                  // Tf2
        whc[(j << 12) + (co << 6) + ci] = (_Float16)v;        // transposed
        return;
    }
    if (blockIdx.x >= NEB) {
        int i = (blockIdx.x - NEB) * 1024 + tid;
        if (i < N_NODES * C / 4) {
            float4 v = ((const float4*)x)[i];
            union { float2 f2; __half2 h2[2]; } u;
            u.h2[0] = __floats2half2_rn(v.x, v.y);
            u.h2[1] = __floats2half2_rn(v.z, v.w);
            int node = i >> 4;
            int ci0 = (i & 15) << 2;            // 0,4,...,60
            int slice = ci0 >> 3;
            int off = ci0 & 7;                  // 0 or 4
            *(float2*)(void*)(xh + (((size_t)slice * NPADL + node) << 3) + off) = u.f2;
        }
        return;
    }
    __shared__ int h[NPART];
    __shared__ int cur[NPART];
    uint2 ent[8];
    int pp[8];
    if (tid < NPART) h[tid] = 0;
    __syncthreads();
    int base = blockIdx.x * EPB;
#pragma unroll
    for (int i = 0; i < 8; ++i) {
        int e = base + i * 1024 + tid;
        pp[i] = -1;
        if (e < N_EDGES) {
            int r = row[e];
            unsigned int c = (unsigned int)col[e];
            unsigned int wh = (unsigned int)__half_as_ushort(__float2half_rn(w[e]));
            ent[i] = make_uint2((c << 16) | wh, (unsigned int)(r & 255));
            pp[i] = r >> 8;
            atomicAdd(&h[pp[i]], 1);
        }
    }
    __syncthreads();
    if (tid < NPART) cur[tid] = atomicAdd(&percur[tid], h[tid]);
    __syncthreads();
#pragma unroll
    for (int i = 0; i < 8; ++i) {
        if (pp[i] >= 0) {
            int slot = atomicAdd(&cur[pp[i]], 1);
            pedges[(size_t)pp[i] * CAPP + slot] = ent[i];
        }
    }
}

// One block per partition: LDS-bin 256 rows x 64 slots, fuse dinv,
// dump only the used slot prefix per row (uint4 chunks).
__global__ __launch_bounds__(1024) void build_kernel(
        const uint2* __restrict__ pedges, const int* __restrict__ percur,
        unsigned int* __restrict__ bkt, int* __restrict__ cnt,
        float* __restrict__ dinv) {
    __shared__ unsigned int lbuck[256 * CAP];   // 64 KB
    __shared__ int lcnt[256];
    const int tid = threadIdx.x;
    const int p = blockIdx.x;
    if (tid < 256) lcnt[tid] = 0;
    __syncthreads();
    int e = min(percur[p], CAPP);
    const uint2* src = pedges + (size_t)p * CAPP;
    for (int i = tid; i < e; i += 1024) {
        uint2 en = src[i];
        int rl = (int)en.y;
        int slot = atomicAdd(&lcnt[rl], 1);
        if (slot < CAP) lbuck[(rl << 6) + slot] = en.x;
    }
    __syncthreads();
    if (tid < 256) {
        int m = min(lcnt[tid], CAP);
        int g = (p << 8) + tid;
        float sum = 0.f;
        for (int j = 0; j < m; ++j)
            sum += __half2float(__ushort_as_half(
                (unsigned short)(lbuck[(tid << 6) + j] & 0xFFFFu)));
        if (g < N_NODES) {
            cnt[g] = m;
            dinv[g] = (sum > 0.f) ? rsqrtf(sum) : 0.f;
        }
    }
    __syncthreads();
    // sparse dump: 4 threads per row, chunk = tid&3; only ceil(m/4) uint4s
    {
        int r = tid >> 2;
        int ch = tid & 3;
        int m = min(lcnt[r], CAP);
        const uint4* s4 = (const uint4*)&lbuck[r << 6];
        uint4* dst = (uint4*)(bkt + (((size_t)(p << 8) + r) << 6));
        for (int j = ch; (j << 2) < m; j += 4) dst[j] = s4[j];
    }
}

// Fold dinv[col] into the stored weight once: bkt2 = (col<<16)|half(w*dinv[col])
__global__ __launch_bounds__(1024) void decode_kernel(
        const unsigned int* __restrict__ bkt, const int* __restrict__ cnt,
        const float* __restrict__ dinv, unsigned int* __restrict__ bkt2) {
    int e = blockIdx.x * 1024 + threadIdx.x;       // < NPADL*64
    int node = e >> 6;
    int j = e & 63;
    if (node < N_NODES && j < min(cnt[node], CAP)) {
        unsigned int b = bkt[e];
        int c = (int)(b >> 16);
        float nn = __half2float(__ushort_as_half((unsigned short)(b & 0xFFFFu)))
                   * dinv[c];
        bkt2[e] = ((unsigned int)c << 16) |
                  (unsigned int)__half_as_ushort(__float2half_rn(nn));
    }
}

// Persistent fused 3-prop kernel. Block = (slice = bid&7, group = bid>>3).
// LDS meta (20 slots/node) decoded once, reused by all 3 props.
// Lane layout: oct=lane>>3 -> node; h=(lane>>2)&1 -> edge parity;
// k2=lane&3 -> channel pair. Gather = half2 (4B/lane, 16B/edge-slice).
// Accumulation lane-local (no tree reduce); h-pair merged with 1 shfl_xor.
__global__ __launch_bounds__(256) void fusedprop_kernel(
        const __half* __restrict__ xh, __half* __restrict__ tA,
        __half* __restrict__ tB, __half* __restrict__ tC,
        const int* __restrict__ cnt, const unsigned int* __restrict__ bkt2,
        const float* __restrict__ dinv, unsigned int* __restrict__ bar) {
    __shared__ unsigned int meta[NPBK * MSLOT];   // 41.7 KB
    __shared__ float drl[NPBK];
    __shared__ unsigned short ml[NPBK];
    const int tid = threadIdx.x;
    const int slice = blockIdx.x & 7;             // perf-only XCD pinning
    const int grp = blockIdx.x >> 3;
    const int n0 = grp * NPBK;
    const int nn = min(NPBK, N_NODES - n0);

    for (int nl = tid; nl < nn; nl += 256) {
        ml[nl] = (unsigned short)min(cnt[n0 + nl], CAP);
        drl[nl] = dinv[n0 + nl];
    }
    __syncthreads();
    for (int e = tid; e < nn * MSLOT; e += 256) {
        int nl = e / MSLOT;
        int j = e - nl * MSLOT;
        unsigned int v = 0;
        if (j < (int)ml[nl]) v = bkt2[(((size_t)(n0 + nl)) << 6) + j];
        meta[e] = v;
    }
    __syncthreads();

    const int w = tid >> 6;
    const int lane = tid & 63;
    const int oct = lane >> 3;
    const int h = (lane >> 2) & 1;
    const int k2 = lane & 3;
    const int iters = (nn + 31) >> 5;

    auto prop = [&](const __half* __restrict__ xin, __half* __restrict__ xout) {
        for (int it = 0; it < iters; ++it) {
            int nl = (it << 5) + (w << 3) + oct;
            bool ok = nl < nn;
            int nls = ok ? nl : 0;
            int m = ok ? (int)ml[nls] : 0;
            int mx = m;
            mx = max(mx, __shfl_xor(mx, 8));
            mx = max(mx, __shfl_xor(mx, 16));
            mx = max(mx, __shfl_xor(mx, 32));
            float ax = 0.f, ay = 0.f;
            int mld = min(mx, MSLOT);
#pragma unroll 2
            for (int r = 0; (r << 1) < mld; ++r) {
                int j = (r << 1) + h;
                if (j < m) {
                    unsigned int mv = meta[nls * MSLOT + j];
                    int c = (int)(mv >> 16);
                    float wv = __half2float(__ushort_as_half(
                        (unsigned short)(mv & 0xFFFFu)));
                    float2 xv = __half22float2(*(const __half2*)(
                        xin + (((size_t)slice * NPADL + c) << 3) + (k2 << 1)));
                    ax += wv * xv.x;
                    ay += wv * xv.y;
                }
            }
            if (mx > MSLOT) {                     // rare tail: m > 20
                for (int r = MSLOT >> 1; (r << 1) < mx; ++r) {
                    int j = (r << 1) + h;
                    if (j < m) {
                        unsigned int mv = bkt2[(((size_t)(n0 + nls)) << 6) + j];
                        int c = (int)(mv >> 16);
                        float wv = __half2float(__ushort_as_half(
                            (unsigned short)(mv & 0xFFFFu)));
                        float2 xv = __half22float2(*(const __half2*)(
                            xin + (((size_t)slice * NPADL + c) << 3) + (k2 << 1)));
                        ax += wv * xv.x;
                        ay += wv * xv.y;
                    }
                }
            }
            ax += __shfl_xor(ax, 4);
            ay += __shfl_xor(ay, 4);
            if (ok && h == 0) {
                float dr = drl[nls];
                *(__half2*)(xout + (((size_t)slice * NPADL + (n0 + nls)) << 3)
                            + (k2 << 1)) = __floats2half2_rn(dr * ax, dr * ay);
            }
        }
    };

    auto gridbar = [&]() {
        __syncthreads();
        if (tid == 0) {
            __threadfence();
            unsigned int gen = __hip_atomic_load(bar + 1, __ATOMIC_RELAXED,
                                                 __HIP_MEMORY_SCOPE_AGENT);
            unsigned int a = __hip_atomic_fetch_add(bar, 1u, __ATOMIC_ACQ_REL,
                                                    __HIP_MEMORY_SCOPE_AGENT);
            if (a == FBLK - 1) {
                __hip_atomic_store(bar, 0u, __ATOMIC_RELAXED,
                                   __HIP_MEMORY_SCOPE_AGENT);
                __hip_atomic_fetch_add(bar + 1, 1u, __ATOMIC_RELEASE,
                                       __HIP_MEMORY_SCOPE_AGENT);
            } else {
                while (__hip_atomic_load(bar + 1, __ATOMIC_ACQUIRE,
                                         __HIP_MEMORY_SCOPE_AGENT) == gen)
                    __builtin_amdgcn_s_sleep(8);
            }
            __threadfence();
        }
        __syncthreads();
    };

    prop(xh, tA);
    gridbar();
    prop(tA, tB);
    gridbar();
    prop(tB, tC);
}

// MFMA GEMM: out[r][co] = sum_j Xj[r][:] @ Wc[j][:][co], slice-major A.
// A-frag: A[m=lane&15][k=quad*8+i] = x[slice=kk/8+quad][row][i] (16B load).
// B-frag: B[k][n=lane&15] from whc[j][n][k..]; C/D: col=lane&15, row=quad*4+reg.
__global__ __launch_bounds__(256) void gemm_mfma_kernel(
        const __half* __restrict__ x0, const __half* __restrict__ x1,
        const __half* __restrict__ x2, const __half* __restrict__ x3,
        const _Float16* __restrict__ whc, float* __restrict__ out) {
    const int tid = threadIdx.x;
    const int wv = tid >> 6;
    const int lane = tid & 63;
    const int quad = lane >> 4;
    const int l16 = lane & 15;
    const int mbase = (blockIdx.x << 6) + (wv << 4);
    const __half* srcs[4] = {x0, x1, x2, x3};
    f32x4 acc0 = {}, acc1 = {}, acc2 = {}, acc3 = {};
    const int arow = mbase + l16;
    const bool aok = arow < N_NODES;
    const half8 zero8 = {};
#pragma unroll
    for (int j = 0; j < 4; ++j) {
        const __half* src = srcs[j];
#pragma unroll
        for (int kk = 0; kk < 64; kk += 32) {
            const int slice = (kk >> 3) + quad;
            half8 af = aok ? *(const half8*)(const void*)(
                src + (((size_t)slice * NPADL + arow) << 3)) : zero8;
            const _Float16* wb = whc + (j << 12) + kk + (quad << 3);
            half8 b0 = *(const half8*)(const void*)(wb + ((0 * 16 + l16) << 6));
            half8 b1 = *(const half8*)(const void*)(wb + ((1 * 16 + l16) << 6));
            half8 b2 = *(const half8*)(const void*)(wb + ((2 * 16 + l16) << 6));
            half8 b3 = *(const half8*)(const void*)(wb + ((3 * 16 + l16) << 6));
            acc0 = __builtin_amdgcn_mfma_f32_16x16x32_f16(af, b0, acc0, 0, 0, 0);
            acc1 = __builtin_amdgcn_mfma_f32_16x16x32_f16(af, b1, acc1, 0, 0, 0);
            acc2 = __builtin_amdgcn_mfma_f32_16x16x32_f16(af, b2, acc2, 0, 0, 0);
            acc3 = __builtin_amdgcn_mfma_f32_16x16x32_f16(af, b3, acc3, 0, 0, 0);
        }
    }
#pragma unroll
    for (int i = 0; i < 4; ++i) {
        int r = mbase + (quad << 2) + i;
        if (r < N_NODES) {
            float* dst = out + ((size_t)r << 6) + l16;
            dst[0]  = acc0[i];
            dst[16] = acc1[i];
            dst[32] = acc2[i];
            dst[48] = acc3[i];
        }
    }
}

extern "C" void kernel_launch(void* const* d_in, const int* in_sizes, int n_in,
                              void* d_out, int out_size, void* d_ws, size_t ws_size,
                              hipStream_t stream) {
    const float* x  = (const float*)d_in[0];
    const int*   ei = (const int*)d_in[1];   // row = ei[0..E), col = ei[E..2E)
    const float* ew = (const float*)d_in[2];
    const float* tf = (const float*)d_in[3];
    const float* tb = (const float*)d_in[4];
    float* out = (float*)d_out;

    const int* row = ei;
    const int* col = ei + N_EDGES;

    // workspace layout (4B words), total ~60 MB
    const size_t TBL = (size_t)NSLICE * NPADL * 8 / 2;   // words per table
    float* ws = (float*)d_ws;
    size_t off = 0;
    int*    percur = (int*)(ws + off); off += 256;
    unsigned int* bar = (unsigned int*)(ws + off); off += 8;
    uint2*  pedges = (uint2*)(ws + off); off += (size_t)NPART * CAPP * 2;
    unsigned int* bkt  = (unsigned int*)(ws + off); off += (size_t)NPADL * CAP;
    unsigned int* bkt2 = (unsigned int*)(ws + off); off += (size_t)NPADL * CAP;
    int*    cnt  = (int*)(ws + off); off += NPADL;
    float*  dinv = ws + off; off += NPADL;
    __half* xh   = (__half*)(ws + off); off += TBL;
    __half* tA   = (__half*)(ws + off); off += TBL;
    __half* tB   = (__half*)(ws + off); off += TBL;
    __half* tC   = (__half*)(ws + off); off += TBL;
    _Float16* whc = (_Float16*)(ws + off); off += 4 * 64 * 64 / 2;

    hipMemsetAsync(percur, 0, (256 + 8) * sizeof(int), stream);

    scatter2_kernel<<<NEB + XH_BLOCKS + CW_BLOCKS, 1024, 0, stream>>>(
        row, col, ew, percur, pedges, x, xh, tf, tb, whc);
    build_kernel<<<NPART, 1024, 0, stream>>>(pedges, percur, bkt, cnt, dinv);
    decode_kernel<<<NPADL * CAP / 1024, 1024, 0, stream>>>(bkt, cnt, dinv, bkt2);

    fusedprop_kernel<<<FBLK, 256, 0, stream>>>(
        xh, tA, tB, tC, cnt, bkt2, dinv, bar);

    gemm_mfma_kernel<<<GB, 256, 0, stream>>>(xh, tA, tB, tC, whc, out);
}

// Round 8
// 190.071 us; speedup vs baseline: 3.5480x; 3.5480x over previous
//
#include <hip/hip_runtime.h>
#include <hip/hip_fp16.h>

// DiffusionConv: out = x@Tf0 + Px@(Tb0+Tb1) + P2x@(Tf1+Tb2) + P3x@Tf2
// R22: merge R18's proven high-ILP prop skeleton with R21's fetch fix.
// R21 post-mortem: slice-major DID cut FETCH (39MB for 3 props, as
// predicted) but the persistent kernel's serial LDS-meta->4B-gather chain
// collapsed ILP (2 loads in flight, 12 waves/CU) -> 190us/prop.
// R22 props: tables [4][NPADL][16ch] (32B rows); block b -> slice b&3,
// tile b>>2; round-robin XCD dispatch pins one slice per XCD (1.6MB,
// L2-resident). Inner loop = R18 structure: register meta prefetch,
// shfl broadcast, 4 independent 8B gathers in flight, no LDS, no
// barriers. decode_kernel folds w*dinv[col] once; 3 identical props.
// gemm separate, slice-major A. scatter2/build verbatim R18 (conversion
// phase writes slice-major).

#define N_NODES 50000
#define N_EDGES 800000
#define C 64
#define CAP 64          // bucket capacity; rows ~ Poisson(16), P(>64) ~ 2e-18
#define NPART 196       // partitions of 256 rows: p = r >> 8
#define CAPP 4608       // edges per partition region; mean 4096, +8 sigma
#define EPB 8192        // edges per block in scatter2
#define NEB 98          // ceil(800000/8192)
#define XH_BLOCKS 782   // ceil(800000 float4 chunks / 1024)
#define CW_BLOCKS 16    // 16384 weight elems / 1024
#define NPADL 50176
#define NSLICE 4        // channel slices of 16; slice = blockIdx&3
#define PB 3125         // node tiles of 16: 50000/16 exactly
#define GB 782          // ceil(50000/64) gemm row-tiles

typedef _Float16 half8 __attribute__((ext_vector_type(8)));
typedef float f32x4 __attribute__((ext_vector_type(4)));

// Fused: blocks [0,NEB): hist+reserve+scatter; [NEB,NEB+XH): x fp32->fp16
// into slice-major xh[4][NPADL][16]; [NEB+XH,..): weights -> whc[j][co][ci]
__global__ __launch_bounds__(1024) void scatter2_kernel(
        const int* __restrict__ row, const int* __restrict__ col,
        const float* __restrict__ w, int* __restrict__ percur,
        uint2* __restrict__ pedges,
        const float* __restrict__ x, __half* __restrict__ xh,
        const float* __restrict__ tf, const float* __restrict__ tb,
        _Float16* __restrict__ whc) {
    const int tid = threadIdx.x;
    if (blockIdx.x >= NEB + XH_BLOCKS) {
        int idx = (blockIdx.x - NEB - XH_BLOCKS) * 1024 + tid;  // < 16384
        int j = idx >> 12;
        int rem = idx & 4095;   // ci*64 + co
        int ci = rem >> 6;
        int co = rem & 63;
        float v;
        if (j == 0)      v = tf[rem];                         // Tf0
        else if (j == 1) v = tb[rem] + tb[4096 + rem];        // Tb0 + Tb1
        else if (j == 2) v = tf[4096 + rem] + tb[8192 + rem]; // Tf1 + Tb2
        else             v = tf[8192 + rem];                  // Tf2
        whc[(j << 12) + (co << 6) + ci] = (_Float16)v;        // transposed
        return;
    }
    if (blockIdx.x >= NEB) {
        int i = (blockIdx.x - NEB) * 1024 + tid;
        if (i < N_NODES * C / 4) {
            float4 v = ((const float4*)x)[i];
            union { float2 f2; __half2 h2[2]; } u;
            u.h2[0] = __floats2half2_rn(v.x, v.y);
            u.h2[1] = __floats2half2_rn(v.z, v.w);
            int node = i >> 4;
            int ci0 = (i & 15) << 2;            // 0,4,...,60
            int slice = ci0 >> 4;
            int off = ci0 & 15;                 // 0,4,8,12
            *(float2*)(void*)(xh + (((size_t)slice * NPADL + node) << 4) + off)
                = u.f2;
        }
        return;
    }
    __shared__ int h[NPART];
    __shared__ int cur[NPART];
    uint2 ent[8];
    int pp[8];
    if (tid < NPART) h[tid] = 0;
    __syncthreads();
    int base = blockIdx.x * EPB;
#pragma unroll
    for (int i = 0; i < 8; ++i) {
        int e = base + i * 1024 + tid;
        pp[i] = -1;
        if (e < N_EDGES) {
            int r = row[e];
            unsigned int c = (unsigned int)col[e];
            unsigned int wh = (unsigned int)__half_as_ushort(__float2half_rn(w[e]));
            ent[i] = make_uint2((c << 16) | wh, (unsigned int)(r & 255));
            pp[i] = r >> 8;
            atomicAdd(&h[pp[i]], 1);
        }
    }
    __syncthreads();
    if (tid < NPART) cur[tid] = atomicAdd(&percur[tid], h[tid]);
    __syncthreads();
#pragma unroll
    for (int i = 0; i < 8; ++i) {
        if (pp[i] >= 0) {
            int slot = atomicAdd(&cur[pp[i]], 1);
            pedges[(size_t)pp[i] * CAPP + slot] = ent[i];
        }
    }
}

// One block per partition: LDS-bin 256 rows x 64 slots, fuse dinv,
// dump only the used slot prefix per row (uint4 chunks).
__global__ __launch_bounds__(1024) void build_kernel(
        const uint2* __restrict__ pedges, const int* __restrict__ percur,
        unsigned int* __restrict__ bkt, int* __restrict__ cnt,
        float* __restrict__ dinv) {
    __shared__ unsigned int lbuck[256 * CAP];   // 64 KB
    __shared__ int lcnt[256];
    const int tid = threadIdx.x;
    const int p = blockIdx.x;
    if (tid < 256) lcnt[tid] = 0;
    __syncthreads();
    int e = min(percur[p], CAPP);
    const uint2* src = pedges + (size_t)p * CAPP;
    for (int i = tid; i < e; i += 1024) {
        uint2 en = src[i];
        int rl = (int)en.y;
        int slot = atomicAdd(&lcnt[rl], 1);
        if (slot < CAP) lbuck[(rl << 6) + slot] = en.x;
    }
    __syncthreads();
    if (tid < 256) {
        int m = min(lcnt[tid], CAP);
        int g = (p << 8) + tid;
        float sum = 0.f;
        for (int j = 0; j < m; ++j)
            sum += __half2float(__ushort_as_half(
                (unsigned short)(lbuck[(tid << 6) + j] & 0xFFFFu)));
        if (g < N_NODES) {
            cnt[g] = m;
            dinv[g] = (sum > 0.f) ? rsqrtf(sum) : 0.f;
        }
    }
    __syncthreads();
    // sparse dump: 4 threads per row, chunk = tid&3; only ceil(m/4) uint4s
    {
        int r = tid >> 2;
        int ch = tid & 3;
        int m = min(lcnt[r], CAP);
        const uint4* s4 = (const uint4*)&lbuck[r << 6];
        uint4* dst = (uint4*)(bkt + (((size_t)(p << 8) + r) << 6));
        for (int j = ch; (j << 2) < m; j += 4) dst[j] = s4[j];
    }
}

// Fold dinv[col] into the stored weight once: bkt2 = (col<<16)|half(w*dinv[col])
__global__ __launch_bounds__(1024) void decode_kernel(
        const unsigned int* __restrict__ bkt, const int* __restrict__ cnt,
        const float* __restrict__ dinv, unsigned int* __restrict__ bkt2) {
    int e = blockIdx.x * 1024 + threadIdx.x;       // < NPADL*64
    int node = e >> 6;
    int j = e & 63;
    if (node < N_NODES && j < min(cnt[node], CAP)) {
        unsigned int b = bkt[e];
        int c = (int)(b >> 16);
        float nn = __half2float(__ushort_as_half((unsigned short)(b & 0xFFFFu)))
                   * dinv[c];
        bkt2[e] = ((unsigned int)c << 16) |
                  (unsigned int)__half_as_ushort(__float2half_rn(nn));
    }
}

// Slice-parallel prop (R18 skeleton): block b -> slice b&3 (16 channels),
// tile b>>2 (16 nodes). Wave = 4 nodes (quarter q); lane ql: u=ql>>2 edge
// subslot, cq=ql&3 channel quad (8B of the 32B slice row). Meta prefetched
// to registers (<=4 strided entries/lane, padded slots c=0,w=0); per
// 16-edge chunk: 8 shfls + 4 independent 8B gathers in flight + FMAs.
// Epilogue: 2-step shfl_xor over u; u==0 lanes write 8B (32B/node/slice).
__global__ __launch_bounds__(256) void prop_kernel(
        const __half* __restrict__ xin, __half* __restrict__ xout,
        const int* __restrict__ cnt, const unsigned int* __restrict__ bkt2,
        const float* __restrict__ dinv) {
    const int tid = threadIdx.x;
    const int wib = tid >> 6;
    const int lane = tid & 63;
    const int q = lane >> 4;
    const int ql = lane & 15;
    const int u = ql >> 2;
    const int cq = ql & 3;
    const int slice = blockIdx.x & 3;
    const int tile = blockIdx.x >> 2;
    const int node = (tile << 4) + (wib << 2) + q;   // < 50000 always
    const int m = min(cnt[node], CAP);
    const int base = node << 6;
    // prefetch all (<=4) strided bucket entries for this lane
    int cj[4];
    float nj[4];
#pragma unroll
    for (int s = 0; s < 4; ++s) {
        int idx = (s << 4) + ql;
        cj[s] = 0;
        nj[s] = 0.f;
        if (idx < m) {
            unsigned int b = bkt2[base + idx];
            cj[s] = (int)(b >> 16) << 4;             // row offset (16 halves/row)
            nj[s] = __half2float(__ushort_as_half((unsigned short)(b & 0xFFFFu)));
        }
    }
    const __half* xsl = xin + ((size_t)slice * NPADL << 4);
    float a0 = 0.f, a1 = 0.f, a2 = 0.f, a3 = 0.f;
#pragma unroll
    for (int s = 0; s < 4; ++s) {
        int cb = s << 4;
        if (cb >= m) break;
        int cs[4];
        float ns[4];
        float2 vs[4];
#pragma unroll
        for (int t = 0; t < 4; ++t) {
            int sl = (q << 4) + (t << 2) + u;        // edge cb+t*4+u lives here
            cs[t] = __shfl(cj[s], sl);
            ns[t] = __shfl(nj[s], sl);
        }
#pragma unroll
        for (int t = 0; t < 4; ++t)
            vs[t] = *(const float2*)(xsl + cs[t] + (cq << 2));
#pragma unroll
        for (int t = 0; t < 4; ++t) {
            const __half2* hp = (const __half2*)&vs[t];
            float2 A = __half22float2(hp[0]);
            float2 B = __half22float2(hp[1]);
            a0 += ns[t] * A.x;
            a1 += ns[t] * A.y;
            a2 += ns[t] * B.x;
            a3 += ns[t] * B.y;
        }
    }
    // reduce over u (lane bits 2,3)
    a0 += __shfl_xor(a0, 4); a0 += __shfl_xor(a0, 8);
    a1 += __shfl_xor(a1, 4); a1 += __shfl_xor(a1, 8);
    a2 += __shfl_xor(a2, 4); a2 += __shfl_xor(a2, 8);
    a3 += __shfl_xor(a3, 4); a3 += __shfl_xor(a3, 8);
    if (u == 0) {
        float dr = dinv[node];
        union { float2 f2; __half2 h2[2]; } o;
        o.h2[0] = __floats2half2_rn(dr * a0, dr * a1);
        o.h2[1] = __floats2half2_rn(dr * a2, dr * a3);
        *(float2*)(void*)(xout + (((size_t)slice * NPADL + node) << 4)
                          + (cq << 2)) = o.f2;
    }
}

// MFMA GEMM: out[r][co] = sum_j Xj[r][:] @ Wc[j][:][co], slice-major A.
// A-frag: A[m=lane&15][k=quad*8+i]: k0=kk+8*quad -> slice k0>>4, off k0&15.
// B-frag: B[k][n=lane&15] from whc[j][n][k..]; C/D: col=lane&15, row=quad*4+reg.
__global__ __launch_bounds__(256) void gemm_mfma_kernel(
        const __half* __restrict__ x0, const __half* __restrict__ x1,
        const __half* __restrict__ x2, const __half* __restrict__ x3,
        const _Float16* __restrict__ whc, float* __restrict__ out) {
    const int tid = threadIdx.x;
    const int wv = tid >> 6;
    const int lane = tid & 63;
    const int quad = lane >> 4;
    const int l16 = lane & 15;
    const int mbase = (blockIdx.x << 6) + (wv << 4);
    const __half* srcs[4] = {x0, x1, x2, x3};
    f32x4 acc0 = {}, acc1 = {}, acc2 = {}, acc3 = {};
    const int arow = mbase + l16;
    const bool aok = arow < N_NODES;
    const half8 zero8 = {};
#pragma unroll
    for (int j = 0; j < 4; ++j) {
        const __half* src = srcs[j];
#pragma unroll
        for (int kk = 0; kk < 64; kk += 32) {
            const int k0 = kk + (quad << 3);
            const int slice = k0 >> 4;
            const int koff = k0 & 15;
            half8 af = aok ? *(const half8*)(const void*)(
                src + (((size_t)slice * NPADL + arow) << 4) + koff) : zero8;
            const _Float16* wb = whc + (j << 12) + kk + (quad << 3);
            half8 b0 = *(const half8*)(const void*)(wb + ((0 * 16 + l16) << 6));
            half8 b1 = *(const half8*)(const void*)(wb + ((1 * 16 + l16) << 6));
            half8 b2 = *(const half8*)(const void*)(wb + ((2 * 16 + l16) << 6));
            half8 b3 = *(const half8*)(const void*)(wb + ((3 * 16 + l16) << 6));
            acc0 = __builtin_amdgcn_mfma_f32_16x16x32_f16(af, b0, acc0, 0, 0, 0);
            acc1 = __builtin_amdgcn_mfma_f32_16x16x32_f16(af, b1, acc1, 0, 0, 0);
            acc2 = __builtin_amdgcn_mfma_f32_16x16x32_f16(af, b2, acc2, 0, 0, 0);
            acc3 = __builtin_amdgcn_mfma_f32_16x16x32_f16(af, b3, acc3, 0, 0, 0);
        }
    }
#pragma unroll
    for (int i = 0; i < 4; ++i) {
        int r = mbase + (quad << 2) + i;
        if (r < N_NODES) {
            float* dst = out + ((size_t)r << 6) + l16;
            dst[0]  = acc0[i];
            dst[16] = acc1[i];
            dst[32] = acc2[i];
            dst[48] = acc3[i];
        }
    }
}

extern "C" void kernel_launch(void* const* d_in, const int* in_sizes, int n_in,
                              void* d_out, int out_size, void* d_ws, size_t ws_size,
                              hipStream_t stream) {
    const float* x  = (const float*)d_in[0];
    const int*   ei = (const int*)d_in[1];   // row = ei[0..E), col = ei[E..2E)
    const float* ew = (const float*)d_in[2];
    const float* tf = (const float*)d_in[3];
    const float* tb = (const float*)d_in[4];
    float* out = (float*)d_out;

    const int* row = ei;
    const int* col = ei + N_EDGES;

    // workspace layout (4B words), total ~59 MB
    const size_t TBL = (size_t)NSLICE * NPADL * 16 / 2;   // words per table
    float* ws = (float*)d_ws;
    size_t off = 0;
    int*    percur = (int*)(ws + off); off += 256;
    uint2*  pedges = (uint2*)(ws + off); off += (size_t)NPART * CAPP * 2;
    unsigned int* bkt  = (unsigned int*)(ws + off); off += (size_t)NPADL * CAP;
    unsigned int* bkt2 = (unsigned int*)(ws + off); off += (size_t)NPADL * CAP;
    int*    cnt  = (int*)(ws + off); off += NPADL;
    float*  dinv = ws + off; off += NPADL;
    __half* xh   = (__half*)(ws + off); off += TBL;
    __half* tA   = (__half*)(ws + off); off += TBL;
    __half* tB   = (__half*)(ws + off); off += TBL;
    __half* tC   = (__half*)(ws + off); off += TBL;
    _Float16* whc = (_Float16*)(ws + off); off += 4 * 64 * 64 / 2;

    hipMemsetAsync(percur, 0, 256 * sizeof(int), stream);

    scatter2_kernel<<<NEB + XH_BLOCKS + CW_BLOCKS, 1024, 0, stream>>>(
        row, col, ew, percur, pedges, x, xh, tf, tb, whc);
    build_kernel<<<NPART, 1024, 0, stream>>>(pedges, percur, bkt, cnt, dinv);
    decode_kernel<<<NPADL * CAP / 1024, 1024, 0, stream>>>(bkt, cnt, dinv, bkt2);

    prop_kernel<<<NSLICE * PB, 256, 0, stream>>>(xh, tA, cnt, bkt2, dinv);  // tx1
    prop_kernel<<<NSLICE * PB, 256, 0, stream>>>(tA, tB, cnt, bkt2, dinv);  // tx2
    prop_kernel<<<NSLICE * PB, 256, 0, stream>>>(tB, tC, cnt, bkt2, dinv);  // tx3

    gemm_mfma_kernel<<<GB, 256, 0, stream>>>(xh, tA, tB, tC, whc, out);
}

// Round 9
// 185.385 us; speedup vs baseline: 3.6376x; 1.0253x over previous
//
#include <hip/hip_runtime.h>
#include <hip/hip_fp16.h>

// DiffusionConv: out = x@Tf0 + Px@(Tb0+Tb1) + P2x@(Tf1+Tb2) + P3x@Tf2
// R23: R22's slice-major layout was right (fetch 42->~26MB, twice
// verified) but its load schedule halved MLP (4 vs 8 loads in flight)
// -> service rate halved (1.4->0.65 TB/s), props 29->40us. R23 keeps
// R22 verbatim EXCEPT the prop inner loop: wave-uniform mx, Phase A
// issues 8 independent 8B gathers (groups 0+1, padded meta makes
// unconditional issue safe), Phase B (mx>32, P~1e-4) covers groups 2+3.
// No per-lane break divergence. Slice=blockIdx&3 pins 1.6MB table slice
// per XCD (round-robin dispatch); decode folds w*dinv[col] once.

#define N_NODES 50000
#define N_EDGES 800000
#define C 64
#define CAP 64          // bucket capacity; rows ~ Poisson(16), P(>64) ~ 2e-18
#define NPART 196       // partitions of 256 rows: p = r >> 8
#define CAPP 4608       // edges per partition region; mean 4096, +8 sigma
#define EPB 8192        // edges per block in scatter2
#define NEB 98          // ceil(800000/8192)
#define XH_BLOCKS 782   // ceil(800000 float4 chunks / 1024)
#define CW_BLOCKS 16    // 16384 weight elems / 1024
#define NPADL 50176
#define NSLICE 4        // channel slices of 16; slice = blockIdx&3
#define PB 3125         // node tiles of 16: 50000/16 exactly
#define GB 782          // ceil(50000/64) gemm row-tiles

typedef _Float16 half8 __attribute__((ext_vector_type(8)));
typedef float f32x4 __attribute__((ext_vector_type(4)));

// Fused: blocks [0,NEB): hist+reserve+scatter; [NEB,NEB+XH): x fp32->fp16
// into slice-major xh[4][NPADL][16]; [NEB+XH,..): weights -> whc[j][co][ci]
__global__ __launch_bounds__(1024) void scatter2_kernel(
        const int* __restrict__ row, const int* __restrict__ col,
        const float* __restrict__ w, int* __restrict__ percur,
        uint2* __restrict__ pedges,
        const float* __restrict__ x, __half* __restrict__ xh,
        const float* __restrict__ tf, const float* __restrict__ tb,
        _Float16* __restrict__ whc) {
    const int tid = threadIdx.x;
    if (blockIdx.x >= NEB + XH_BLOCKS) {
        int idx = (blockIdx.x - NEB - XH_BLOCKS) * 1024 + tid;  // < 16384
        int j = idx >> 12;
        int rem = idx & 4095;   // ci*64 + co
        int ci = rem >> 6;
        int co = rem & 63;
        float v;
        if (j == 0)      v = tf[rem];                         // Tf0
        else if (j == 1) v = tb[rem] + tb[4096 + rem];        // Tb0 + Tb1
        else if (j == 2) v = tf[4096 + rem] + tb[8192 + rem]; // Tf1 + Tb2
        else             v = tf[8192 + rem];                  // Tf2
        whc[(j << 12) + (co << 6) + ci] = (_Float16)v;        // transposed
        return;
    }
    if (blockIdx.x >= NEB) {
        int i = (blockIdx.x - NEB) * 1024 + tid;
        if (i < N_NODES * C / 4) {
            float4 v = ((const float4*)x)[i];
            union { float2 f2; __half2 h2[2]; } u;
            u.h2[0] = __floats2half2_rn(v.x, v.y);
            u.h2[1] = __floats2half2_rn(v.z, v.w);
            int node = i >> 4;
            int ci0 = (i & 15) << 2;            // 0,4,...,60
            int slice = ci0 >> 4;
            int off = ci0 & 15;                 // 0,4,8,12
            *(float2*)(void*)(xh + (((size_t)slice * NPADL + node) << 4) + off)
                = u.f2;
        }
        return;
    }
    __shared__ int h[NPART];
    __shared__ int cur[NPART];
    uint2 ent[8];
    int pp[8];
    if (tid < NPART) h[tid] = 0;
    __syncthreads();
    int base = blockIdx.x * EPB;
#pragma unroll
    for (int i = 0; i < 8; ++i) {
        int e = base + i * 1024 + tid;
        pp[i] = -1;
        if (e < N_EDGES) {
            int r = row[e];
            unsigned int c = (unsigned int)col[e];
            unsigned int wh = (unsigned int)__half_as_ushort(__float2half_rn(w[e]));
            ent[i] = make_uint2((c << 16) | wh, (unsigned int)(r & 255));
            pp[i] = r >> 8;
            atomicAdd(&h[pp[i]], 1);
        }
    }
    __syncthreads();
    if (tid < NPART) cur[tid] = atomicAdd(&percur[tid], h[tid]);
    __syncthreads();
#pragma unroll
    for (int i = 0; i < 8; ++i) {
        if (pp[i] >= 0) {
            int slot = atomicAdd(&cur[pp[i]], 1);
            pedges[(size_t)pp[i] * CAPP + slot] = ent[i];
        }
    }
}

// One block per partition: LDS-bin 256 rows x 64 slots, fuse dinv,
// dump only the used slot prefix per row (uint4 chunks).
__global__ __launch_bounds__(1024) void build_kernel(
        const uint2* __restrict__ pedges, const int* __restrict__ percur,
        unsigned int* __restrict__ bkt, int* __restrict__ cnt,
        float* __restrict__ dinv) {
    __shared__ unsigned int lbuck[256 * CAP];   // 64 KB
    __shared__ int lcnt[256];
    const int tid = threadIdx.x;
    const int p = blockIdx.x;
    if (tid < 256) lcnt[tid] = 0;
    __syncthreads();
    int e = min(percur[p], CAPP);
    const uint2* src = pedges + (size_t)p * CAPP;
    for (int i = tid; i < e; i += 1024) {
        uint2 en = src[i];
        int rl = (int)en.y;
        int slot = atomicAdd(&lcnt[rl], 1);
        if (slot < CAP) lbuck[(rl << 6) + slot] = en.x;
    }
    __syncthreads();
    if (tid < 256) {
        int m = min(lcnt[tid], CAP);
        int g = (p << 8) + tid;
        float sum = 0.f;
        for (int j = 0; j < m; ++j)
            sum += __half2float(__ushort_as_half(
                (unsigned short)(lbuck[(tid << 6) + j] & 0xFFFFu)));
        if (g < N_NODES) {
            cnt[g] = m;
            dinv[g] = (sum > 0.f) ? rsqrtf(sum) : 0.f;
        }
    }
    __syncthreads();
    // sparse dump: 4 threads per row, chunk = tid&3; only ceil(m/4) uint4s
    {
        int r = tid >> 2;
        int ch = tid & 3;
        int m = min(lcnt[r], CAP);
        const uint4* s4 = (const uint4*)&lbuck[r << 6];
        uint4* dst = (uint4*)(bkt + (((size_t)(p << 8) + r) << 6));
        for (int j = ch; (j << 2) < m; j += 4) dst[j] = s4[j];
    }
}

// Fold dinv[col] into the stored weight once: bkt2 = (col<<16)|half(w*dinv[col])
__global__ __launch_bounds__(1024) void decode_kernel(
        const unsigned int* __restrict__ bkt, const int* __restrict__ cnt,
        const float* __restrict__ dinv, unsigned int* __restrict__ bkt2) {
    int e = blockIdx.x * 1024 + threadIdx.x;       // < NPADL*64
    int node = e >> 6;
    int j = e & 63;
    if (node < N_NODES && j < min(cnt[node], CAP)) {
        unsigned int b = bkt[e];
        int c = (int)(b >> 16);
        float nn = __half2float(__ushort_as_half((unsigned short)(b & 0xFFFFu)))
                   * dinv[c];
        bkt2[e] = ((unsigned int)c << 16) |
                  (unsigned int)__half_as_ushort(__float2half_rn(nn));
    }
}

// Slice-parallel prop, full-MLP schedule: block b -> slice b&3 (16 ch),
// tile b>>2 (16 nodes). Wave = 4 nodes (quarter q); lane ql: u=ql>>2 edge
// subslot, cq=ql&3 channel quad. Meta prefetched to regs (<=4 strided
// entries/lane, padded c=0,w=0). Phase A: groups 0+1 -> 16 shfl-pairs,
// then 8 INDEPENDENT 8B gathers in flight, then FMAs. Phase B (wave-
// uniform mx>32, P~1e-4): groups 2+3. Epilogue: 2-step shfl_xor over u;
// u==0 lanes write 8B.
__global__ __launch_bounds__(256) void prop_kernel(
        const __half* __restrict__ xin, __half* __restrict__ xout,
        const int* __restrict__ cnt, const unsigned int* __restrict__ bkt2,
        const float* __restrict__ dinv) {
    const int tid = threadIdx.x;
    const int wib = tid >> 6;
    const int lane = tid & 63;
    const int q = lane >> 4;
    const int ql = lane & 15;
    const int u = ql >> 2;
    const int cq = ql & 3;
    const int slice = blockIdx.x & 3;
    const int tile = blockIdx.x >> 2;
    const int node = (tile << 4) + (wib << 2) + q;   // < 50000 always
    const int m = min(cnt[node], CAP);
    const int base = node << 6;
    // prefetch all (<=4) strided bucket entries for this lane (padded)
    int cj[4];
    float nj[4];
#pragma unroll
    for (int s = 0; s < 4; ++s) {
        int idx = (s << 4) + ql;
        cj[s] = 0;
        nj[s] = 0.f;
        if (idx < m) {
            unsigned int b = bkt2[base + idx];
            cj[s] = (int)(b >> 16) << 4;             // row offset (16 halves/row)
            nj[s] = __half2float(__ushort_as_half((unsigned short)(b & 0xFFFFu)));
        }
    }
    int mx = m;
    mx = max(mx, __shfl_xor(mx, 16));
    mx = max(mx, __shfl_xor(mx, 32));                // max over wave's 4 nodes
    const __half* xsl = xin + ((size_t)slice * NPADL << 4);
    float a0 = 0.f, a1 = 0.f, a2 = 0.f, a3 = 0.f;
    // ---- Phase A: groups 0,1 (edges 0..31), 8 loads in flight ----
    {
        int cs[8];
        float ns[8];
        float2 vs[8];
#pragma unroll
        for (int g = 0; g < 2; ++g)
#pragma unroll
            for (int t = 0; t < 4; ++t) {
                int i = (g << 2) + t;
                int sl = (q << 4) + (t << 2) + u;    // edge g*16 + t*4+u
                cs[i] = __shfl(cj[g], sl);
                ns[i] = __shfl(nj[g], sl);
            }
#pragma unroll
        for (int i = 0; i < 8; ++i)
            vs[i] = *(const float2*)(xsl + cs[i] + (cq << 2));
#pragma unroll
        for (int i = 0; i < 8; ++i) {
            const __half2* hp = (const __half2*)&vs[i];
            float2 A = __half22float2(hp[0]);
            float2 B = __half22float2(hp[1]);
            a0 += ns[i] * A.x;
            a1 += ns[i] * A.y;
            a2 += ns[i] * B.x;
            a3 += ns[i] * B.y;
        }
    }
    // ---- Phase B: groups 2,3 (edges 32..63), rare ----
    if (mx > 32) {
        int cs[8];
        float ns[8];
        float2 vs[8];
#pragma unroll
        for (int g = 0; g < 2; ++g)
#pragma unroll
            for (int t = 0; t < 4; ++t) {
                int i = (g << 2) + t;
                int sl = (q << 4) + (t << 2) + u;
                cs[i] = __shfl(cj[2 + g], sl);
                ns[i] = __shfl(nj[2 + g], sl);
            }
#pragma unroll
        for (int i = 0; i < 8; ++i)
            vs[i] = *(const float2*)(xsl + cs[i] + (cq << 2));
#pragma unroll
        for (int i = 0; i < 8; ++i) {
            const __half2* hp = (const __half2*)&vs[i];
            float2 A = __half22float2(hp[0]);
            float2 B = __half22float2(hp[1]);
            a0 += ns[i] * A.x;
            a1 += ns[i] * A.y;
            a2 += ns[i] * B.x;
            a3 += ns[i] * B.y;
        }
    }
    // reduce over u (lane bits 2,3)
    a0 += __shfl_xor(a0, 4); a0 += __shfl_xor(a0, 8);
    a1 += __shfl_xor(a1, 4); a1 += __shfl_xor(a1, 8);
    a2 += __shfl_xor(a2, 4); a2 += __shfl_xor(a2, 8);
    a3 += __shfl_xor(a3, 4); a3 += __shfl_xor(a3, 8);
    if (u == 0) {
        float dr = dinv[node];
        union { float2 f2; __half2 h2[2]; } o;
        o.h2[0] = __floats2half2_rn(dr * a0, dr * a1);
        o.h2[1] = __floats2half2_rn(dr * a2, dr * a3);
        *(float2*)(void*)(xout + (((size_t)slice * NPADL + node) << 4)
                          + (cq << 2)) = o.f2;
    }
}

// MFMA GEMM: out[r][co] = sum_j Xj[r][:] @ Wc[j][:][co], slice-major A.
// A-frag: A[m=lane&15][k=quad*8+i]: k0=kk+8*quad -> slice k0>>4, off k0&15.
// B-frag: B[k][n=lane&15] from whc[j][n][k..]; C/D: col=lane&15, row=quad*4+reg.
__global__ __launch_bounds__(256) void gemm_mfma_kernel(
        const __half* __restrict__ x0, const __half* __restrict__ x1,
        const __half* __restrict__ x2, const __half* __restrict__ x3,
        const _Float16* __restrict__ whc, float* __restrict__ out) {
    const int tid = threadIdx.x;
    const int wv = tid >> 6;
    const int lane = tid & 63;
    const int quad = lane >> 4;
    const int l16 = lane & 15;
    const int mbase = (blockIdx.x << 6) + (wv << 4);
    const __half* srcs[4] = {x0, x1, x2, x3};
    f32x4 acc0 = {}, acc1 = {}, acc2 = {}, acc3 = {};
    const int arow = mbase + l16;
    const bool aok = arow < N_NODES;
    const half8 zero8 = {};
#pragma unroll
    for (int j = 0; j < 4; ++j) {
        const __half* src = srcs[j];
#pragma unroll
        for (int kk = 0; kk < 64; kk += 32) {
            const int k0 = kk + (quad << 3);
            const int slice = k0 >> 4;
            const int koff = k0 & 15;
            half8 af = aok ? *(const half8*)(const void*)(
                src + (((size_t)slice * NPADL + arow) << 4) + koff) : zero8;
            const _Float16* wb = whc + (j << 12) + kk + (quad << 3);
            half8 b0 = *(const half8*)(const void*)(wb + ((0 * 16 + l16) << 6));
            half8 b1 = *(const half8*)(const void*)(wb + ((1 * 16 + l16) << 6));
            half8 b2 = *(const half8*)(const void*)(wb + ((2 * 16 + l16) << 6));
            half8 b3 = *(const half8*)(const void*)(wb + ((3 * 16 + l16) << 6));
            acc0 = __builtin_amdgcn_mfma_f32_16x16x32_f16(af, b0, acc0, 0, 0, 0);
            acc1 = __builtin_amdgcn_mfma_f32_16x16x32_f16(af, b1, acc1, 0, 0, 0);
            acc2 = __builtin_amdgcn_mfma_f32_16x16x32_f16(af, b2, acc2, 0, 0, 0);
            acc3 = __builtin_amdgcn_mfma_f32_16x16x32_f16(af, b3, acc3, 0, 0, 0);
        }
    }
#pragma unroll
    for (int i = 0; i < 4; ++i) {
        int r = mbase + (quad << 2) + i;
        if (r < N_NODES) {
            float* dst = out + ((size_t)r << 6) + l16;
            dst[0]  = acc0[i];
            dst[16] = acc1[i];
            dst[32] = acc2[i];
            dst[48] = acc3[i];
        }
    }
}

extern "C" void kernel_launch(void* const* d_in, const int* in_sizes, int n_in,
                              void* d_out, int out_size, void* d_ws, size_t ws_size,
                              hipStream_t stream) {
    const float* x  = (const float*)d_in[0];
    const int*   ei = (const int*)d_in[1];   // row = ei[0..E), col = ei[E..2E)
    const float* ew = (const float*)d_in[2];
    const float* tf = (const float*)d_in[3];
    const float* tb = (const float*)d_in[4];
    float* out = (float*)d_out;

    const int* row = ei;
    const int* col = ei + N_EDGES;

    // workspace layout (4B words), total ~59 MB
    const size_t TBL = (size_t)NSLICE * NPADL * 16 / 2;   // words per table
    float* ws = (float*)d_ws;
    size_t off = 0;
    int*    percur = (int*)(ws + off); off += 256;
    uint2*  pedges = (uint2*)(ws + off); off += (size_t)NPART * CAPP * 2;
    unsigned int* bkt  = (unsigned int*)(ws + off); off += (size_t)NPADL * CAP;
    unsigned int* bkt2 = (unsigned int*)(ws + off); off += (size_t)NPADL * CAP;
    int*    cnt  = (int*)(ws + off); off += NPADL;
    float*  dinv = ws + off; off += NPADL;
    __half* xh   = (__half*)(ws + off); off += TBL;
    __half* tA   = (__half*)(ws + off); off += TBL;
    __half* tB   = (__half*)(ws + off); off += TBL;
    __half* tC   = (__half*)(ws + off); off += TBL;
    _Float16* whc = (_Float16*)(ws + off); off += 4 * 64 * 64 / 2;

    hipMemsetAsync(percur, 0, 256 * sizeof(int), stream);

    scatter2_kernel<<<NEB + XH_BLOCKS + CW_BLOCKS, 1024, 0, stream>>>(
        row, col, ew, percur, pedges, x, xh, tf, tb, whc);
    build_kernel<<<NPART, 1024, 0, stream>>>(pedges, percur, bkt, cnt, dinv);
    decode_kernel<<<NPADL * CAP / 1024, 1024, 0, stream>>>(bkt, cnt, dinv, bkt2);

    prop_kernel<<<NSLICE * PB, 256, 0, stream>>>(xh, tA, cnt, bkt2, dinv);  // tx1
    prop_kernel<<<NSLICE * PB, 256, 0, stream>>>(tA, tB, cnt, bkt2, dinv);  // tx2
    prop_kernel<<<NSLICE * PB, 256, 0, stream>>>(tB, tC, cnt, bkt2, dinv);  // tx3

    gemm_mfma_kernel<<<GB, 256, 0, stream>>>(xh, tA, tB, tC, whc, out);
}